// Round 1
// 2541.834 us; speedup vs baseline: 1.0050x; 1.0050x over previous
//
#include <hip/hip_runtime.h>

#define DEVI __device__ __forceinline__
typedef float f2 __attribute__((ext_vector_type(2)));

// ---------------- problem constants ----------------
constexpr int T_ = 4096, B_ = 128;
constexpr int CH = 4, NCH = T_ / CH;   // 1024 chunks of 4 timesteps
constexpr int NSTEP2 = 1040;           // >= NCH + 15 stages, even
constexpr int XROW = 68;               // x row padded 64->68 dwords

// One batch per workgroup. LDS strides in floats.
// y1/xw layer block: [2][CH][20] -> sl*80 + tt*20 + j
// y2 layer block:    [2][CH][12] -> sl*48 + tt*12 + j  (slots 10,11 are zero pads)
constexpr int Y1L = 160, Y2L = 96;

struct P {
  const float* x;
  const float* w1; const float* b1;    // wih0 (20x64), bih0 (20)
  const float* wih[31]; const float* whh[31];
  const float* bih[31]; const float* bhh[31];
  float* out;
};

DEVI float ftanh(float x) {
  float e = __builtin_amdgcn_exp2f(x * 2.8853900817779268f);
  return 1.0f - 2.0f * __builtin_amdgcn_rcpf(e + 1.0f);
}

DEVI f2 pfma(f2 a, f2 b, f2 c) { return __builtin_elementwise_fma(a, b, c); }

// half-dot over 10 floats (one half of a 20-dot): 5 ds_read_b64 + 5 v_pk_fma
DEVI void acc20h(f2& a, const float* r, const f2* w) {
#pragma unroll
  for (int q = 0; q < 5; q++) {
    float2 v = ((const float2*)r)[q];
    f2 t; t.x = v.x; t.y = v.y;
    a = pfma(t, w[q], a);
  }
}

// half-dot over 6 slots (one half of a 12-slot row; slots 10,11 zero-padded)
DEVI void acc12h(f2& a, const float* r, const f2* w) {
#pragma unroll
  for (int q = 0; q < 3; q++) {
    float2 v = ((const float2*)r)[q];
    f2 t; t.x = v.x; t.y = v.y;
    a = pfma(t, w[q], a);
  }
}

// combine the two lane-halves (lane j <-> lane j^32); both halves get the full sum
DEVI float redsum(f2 a, int pidx) {
  float s = a.x + a.y;
  return s + __int_as_float(__builtin_amdgcn_ds_bpermute(pidx, __float_as_int(s)));
}

// ================= wave 0: x staging + input projection =================
template <int SL>
DEVI void proj_chunk(const float* xbh, float* xww, const f2* wp, float bp, int pidx) {
#pragma unroll
  for (int tt = 0; tt < CH; tt++) {
    const float* xr = xbh + SL * (CH * XROW) + tt * XROW;
    f2 a; a.x = bp; a.y = 0.f;
#pragma unroll
    for (int q = 0; q < 8; q++) {
      float4 v = ((const float4*)xr)[q];
      union { float4 f; f2 h[2]; } u; u.f = v;
      a = pfma(u.h[0], wp[2 * q], a);
      a = pfma(u.h[1], wp[2 * q + 1], a);
    }
    xww[SL * 80 + tt * 20] = redsum(a, pidx);
  }
}

DEVI void stage_proj(const P& p, int b, int lane, float* xb, float* xwf) {
  const int jj = lane & 31;
  const bool act = jj < 20;
  const bool hi = lane >= 32;
  const int pidx = (lane ^ 32) << 2;
  const int j = act ? jj : 19;
  const int ko = hi ? 32 : 0;
  f2 wp[16];
#pragma unroll
  for (int k = 0; k < 16; k++) {
    wp[k].x = p.w1[j * 64 + ko + 2 * k]; wp[k].y = p.w1[j * 64 + ko + 2 * k + 1];
  }
  const float bp = hi ? 0.f : p.b1[j];
  float* xww = xwf + j;
  const float* xbh = xb + ko;

  // staging: all 64 lanes, one float4 each covers CH*64 = 256 floats
  const int tq = lane >> 4, qq = lane & 15;
  const float* src = p.x + (size_t)tq * (B_ * 64) + (size_t)b * 64 + qq * 4;
  const int dst = tq * XROW + qq * 4;
  float4 pf = *(const float4*)src;
  *(float4*)(xb + dst) = pf;
  src += CH * B_ * 64;

  for (int s = 0; s < NSTEP2; s += 2) {
    {  // phase A: c = s, slot 0
      const int c = s;
      if (c < NCH) {
        const bool more = (c + 1 < NCH);
        float4 nx;
        if (more) { nx = *(const float4*)src; src += CH * B_ * 64; }
        if (act) proj_chunk<0>(xbh, xww, wp, bp, pidx);
        if (more) *(float4*)(xb + CH * XROW + dst) = nx;  // slot 1
      }
      __syncthreads();
    }
    {  // phase B: c = s+1, slot 1
      const int c = s + 1;
      if (c < NCH) {
        const bool more = (c + 1 < NCH);
        float4 nx;
        if (more) { nx = *(const float4*)src; src += CH * B_ * 64; }
        if (act) proj_chunk<1>(xbh, xww, wp, bp, pidx);
        if (more) *(float4*)(xb + dst) = nx;  // slot 0
      }
      __syncthreads();
    }
  }
}

// ================= stack1 pair wave (2 layers, H=20) =================
template <int SL, bool FIRST>
DEVI void pair_chunk(const float* yin, const float* yAr, float* yAw,
                     const float* yBr, float* yBw,
                     const f2* wiA, const f2* whA, const f2* wiB, const f2* whB,
                     float bA, float bB, bool hi, int pidx) {
#pragma unroll
  for (int tt = 0; tt < CH; tt++) {
    const int IN = SL * 80 + tt * 20;
    const int PV = tt ? (SL * 80 + (tt - 1) * 20) : ((1 - SL) * 80 + 60);
    f2 a; a.x = bA; a.y = 0.f;
    if constexpr (FIRST) { const float pick = yin[IN]; if (!hi) a.x += pick; }
    else acc20h(a, yin + IN, wiA);
    acc20h(a, yAr + PV, whA);
    const float hA = ftanh(redsum(a, pidx));
    yAw[IN] = hA;                       // both halves write same value
    f2 bb; bb.x = bB; bb.y = 0.f;
    acc20h(bb, yAr + IN, wiB);          // reads row just written (same wave, DS-ordered)
    acc20h(bb, yBr + PV, whB);
    const float hB = ftanh(redsum(bb, pidx));
    yBw[IN] = hB;
  }
}

template <bool PH, bool FIRST>
DEVI void pair_s1(int la, int w, const P& p, int lane, float* y1f, float* xwf) {
  const int jj = lane & 31;
  const bool act = jj < 20;
  const bool hi = lane >= 32;
  const int pidx = (lane ^ 32) << 2;
  const int j = act ? jj : 19;
  const int ko = hi ? 10 : 0;
  const int lb = la + 1;
  f2 whA[5], whB[5], wiB[5], wiA[FIRST ? 1 : 5];
#pragma unroll
  for (int k = 0; k < 5; k++) {
    whA[k].x = p.whh[la][j * 20 + ko + 2 * k]; whA[k].y = p.whh[la][j * 20 + ko + 2 * k + 1];
    whB[k].x = p.whh[lb][j * 20 + ko + 2 * k]; whB[k].y = p.whh[lb][j * 20 + ko + 2 * k + 1];
    wiB[k].x = p.wih[lb][j * 20 + ko + 2 * k]; wiB[k].y = p.wih[lb][j * 20 + ko + 2 * k + 1];
    if constexpr (!FIRST) {
      wiA[k].x = p.wih[la][j * 20 + ko + 2 * k]; wiA[k].y = p.wih[la][j * 20 + ko + 2 * k + 1];
    }
  }
  float bA = p.bhh[la][j];
  if constexpr (!FIRST) bA += p.bih[la][j];  // L0: bih folded into projection
  float bB = p.bih[lb][j] + p.bhh[lb][j];
  if (hi) { bA = 0.f; bB = 0.f; }

  const float* yin = FIRST ? (xwf + j) : (y1f + (la - 1) * Y1L + ko);
  const float* yAr = y1f + la * Y1L + ko;
  float*       yAw = y1f + la * Y1L + j;
  const float* yBr = y1f + lb * Y1L + ko;
  float*       yBw = y1f + lb * Y1L + j;
  if (act) { yAw[140] = 0.f; yBw[140] = 0.f; }  // zero slot[1][CH-1] => drop t>0 branch

  for (int s = 0; s < NSTEP2; s += 2) {
    if ((unsigned)(s - w) < (unsigned)NCH && act)
      pair_chunk<PH ? 1 : 0, FIRST>(yin, yAr, yAw, yBr, yBw, wiA, whA, wiB, whB, bA, bB, hi, pidx);
    __syncthreads();
    if ((unsigned)(s + 1 - w) < (unsigned)NCH && act)
      pair_chunk<PH ? 0 : 1, FIRST>(yin, yAr, yAw, yBr, yBw, wiA, whA, wiB, whB, bA, bB, hi, pidx);
    __syncthreads();
  }
}

// ================= wave 11: L20 (20->10) + L21 + L22 =================
template <int SL>
DEVI void tri20_chunk(const float* y19, const float* y0r, float* y0w,
                      const float* y1r, float* y1w, const float* y2r, float* y2w,
                      const f2* wi0, const f2* wh0, const f2* wi1, const f2* wh1,
                      const f2* wi2, const f2* wh2,
                      float b0, float b1, float b2, int pidx) {
#pragma unroll
  for (int tt = 0; tt < CH; tt++) {
    const int IN1 = SL * 80 + tt * 20;
    const int IN2 = SL * 48 + tt * 12;
    const int PV2 = tt ? (SL * 48 + (tt - 1) * 12) : ((1 - SL) * 48 + 36);
    f2 a; a.x = b0; a.y = 0.f;
    acc20h(a, y19 + IN1, wi0);
    acc12h(a, y0r + PV2, wh0);
    float h = ftanh(redsum(a, pidx));
    y0w[IN2] = h;
    a.x = b1; a.y = 0.f;
    acc12h(a, y0r + IN2, wi1);
    acc12h(a, y1r + PV2, wh1);
    h = ftanh(redsum(a, pidx));
    y1w[IN2] = h;
    a.x = b2; a.y = 0.f;
    acc12h(a, y1r + IN2, wi2);
    acc12h(a, y2r + PV2, wh2);
    h = ftanh(redsum(a, pidx));
    y2w[IN2] = h;
  }
}

template <bool PH>
DEVI void tri20(const P& p, int w, int lane, float* y1f, float* y2f) {
  const int jj = lane & 31;
  const bool act = jj < 10;
  const bool hi = lane >= 32;
  const int pidx = (lane ^ 32) << 2;
  const int j = act ? jj : 9;
  const int ko1 = hi ? 10 : 0;
  const int ko2 = hi ? 6 : 0;
  f2 wi0[5], wh0[3], wi1[3], wh1[3], wi2[3], wh2[3];
#pragma unroll
  for (int k = 0; k < 5; k++) {
    wi0[k].x = p.wih[20][j * 20 + ko1 + 2 * k]; wi0[k].y = p.wih[20][j * 20 + ko1 + 2 * k + 1];
  }
#pragma unroll
  for (int k = 0; k < 3; k++) {
    const int i0 = ko2 + 2 * k, i1 = i0 + 1;
    wh0[k].x = i0 < 10 ? p.whh[20][j * 10 + i0] : 0.f; wh0[k].y = i1 < 10 ? p.whh[20][j * 10 + i1] : 0.f;
    wi1[k].x = i0 < 10 ? p.wih[21][j * 10 + i0] : 0.f; wi1[k].y = i1 < 10 ? p.wih[21][j * 10 + i1] : 0.f;
    wh1[k].x = i0 < 10 ? p.whh[21][j * 10 + i0] : 0.f; wh1[k].y = i1 < 10 ? p.whh[21][j * 10 + i1] : 0.f;
    wi2[k].x = i0 < 10 ? p.wih[22][j * 10 + i0] : 0.f; wi2[k].y = i1 < 10 ? p.wih[22][j * 10 + i1] : 0.f;
    wh2[k].x = i0 < 10 ? p.whh[22][j * 10 + i0] : 0.f; wh2[k].y = i1 < 10 ? p.whh[22][j * 10 + i1] : 0.f;
  }
  float b0 = p.bih[20][j] + p.bhh[20][j];
  float b1 = p.bih[21][j] + p.bhh[21][j];
  float b2 = p.bih[22][j] + p.bhh[22][j];
  if (hi) { b0 = 0.f; b1 = 0.f; b2 = 0.f; }

  const float* y19 = y1f + 19 * Y1L + ko1;
  const float* y0r = y2f + 0 * Y2L + ko2;  float* y0w = y2f + 0 * Y2L + j;
  const float* y1r = y2f + 1 * Y2L + ko2;  float* y1w = y2f + 1 * Y2L + j;
  const float* y2r = y2f + 2 * Y2L + ko2;  float* y2w = y2f + 2 * Y2L + j;

  // zero ALL of y2 once (carry rows AND the [10],[11] pad slots read by hi halves);
  // consumers first read >= 12 barriers later, so this is race-free.
  for (int q = lane; q < 10 * Y2L; q += 64) y2f[q] = 0.f;

  for (int s = 0; s < NSTEP2; s += 2) {
    if ((unsigned)(s - w) < (unsigned)NCH && act)
      tri20_chunk<PH ? 1 : 0>(y19, y0r, y0w, y1r, y1w, y2r, y2w,
                              wi0, wh0, wi1, wh1, wi2, wh2, b0, b1, b2, pidx);
    __syncthreads();
    if ((unsigned)(s + 1 - w) < (unsigned)NCH && act)
      tri20_chunk<PH ? 0 : 1>(y19, y0r, y0w, y1r, y1w, y2r, y2w,
                              wi0, wh0, wi1, wh1, wi2, wh2, b0, b1, b2, pidx);
    __syncthreads();
  }
}

// ================= waves 12/13: three H=10 layers =================
template <int SL>
DEVI void tri_chunk(const float* yi0, const float* r0, float* w0,
                    const float* r1, float* w1, const float* r2, float* w2,
                    const f2 wi[3][3], const f2 wh[3][3], const float* bs, int pidx) {
#pragma unroll
  for (int tt = 0; tt < CH; tt++) {
    const int IN2 = SL * 48 + tt * 12;
    const int PV2 = tt ? (SL * 48 + (tt - 1) * 12) : ((1 - SL) * 48 + 36);
    f2 a; a.x = bs[0]; a.y = 0.f;
    acc12h(a, yi0 + IN2, wi[0]);
    acc12h(a, r0 + PV2, wh[0]);
    float h = ftanh(redsum(a, pidx));
    w0[IN2] = h;
    a.x = bs[1]; a.y = 0.f;
    acc12h(a, r0 + IN2, wi[1]);
    acc12h(a, r1 + PV2, wh[1]);
    h = ftanh(redsum(a, pidx));
    w1[IN2] = h;
    a.x = bs[2]; a.y = 0.f;
    acc12h(a, r1 + IN2, wi[2]);
    acc12h(a, r2 + PV2, wh[2]);
    h = ftanh(redsum(a, pidx));
    w2[IN2] = h;
  }
}

template <bool PH>
DEVI void tri_s2(int l0, int w, const P& p, int lane, float* y2f) {
  const int jj = lane & 31;
  const bool act = jj < 10;
  const bool hi = lane >= 32;
  const int pidx = (lane ^ 32) << 2;
  const int j = act ? jj : 9;
  const int ko2 = hi ? 6 : 0;
  f2 wi[3][3], wh[3][3];
  float bs[3];
#pragma unroll
  for (int m = 0; m < 3; m++) {
    const int l = l0 + m;
#pragma unroll
    for (int k = 0; k < 3; k++) {
      const int i0 = ko2 + 2 * k, i1 = i0 + 1;
      wi[m][k].x = i0 < 10 ? p.wih[l][j * 10 + i0] : 0.f; wi[m][k].y = i1 < 10 ? p.wih[l][j * 10 + i1] : 0.f;
      wh[m][k].x = i0 < 10 ? p.whh[l][j * 10 + i0] : 0.f; wh[m][k].y = i1 < 10 ? p.whh[l][j * 10 + i1] : 0.f;
    }
    bs[m] = hi ? 0.f : (p.bih[l][j] + p.bhh[l][j]);
  }
  const int bi = l0 - 21;  // input ring index
  const float* yi0 = y2f + bi * Y2L + ko2;
  const float* r0 = y2f + (bi + 1) * Y2L + ko2;  float* w0 = y2f + (bi + 1) * Y2L + j;
  const float* r1 = y2f + (bi + 2) * Y2L + ko2;  float* w1 = y2f + (bi + 2) * Y2L + j;
  const float* r2 = y2f + (bi + 3) * Y2L + ko2;  float* w2 = y2f + (bi + 3) * Y2L + j;

  for (int s = 0; s < NSTEP2; s += 2) {
    if ((unsigned)(s - w) < (unsigned)NCH && act)
      tri_chunk<PH ? 1 : 0>(yi0, r0, w0, r1, w1, r2, w2, wi, wh, bs, pidx);
    __syncthreads();
    if ((unsigned)(s + 1 - w) < (unsigned)NCH && act)
      tri_chunk<PH ? 0 : 1>(yi0, r0, w0, r1, w1, r2, w2, wi, wh, bs, pidx);
    __syncthreads();
  }
}

// ================= wave 14: L29 (H=10) + L30 (H=1) + stores =================
template <int SL>
DEVI void tail_chunk(const float* y8r, const float* y9r, float* y9w,
                     const f2* wi29, const f2* wh29, const f2* wi30,
                     float b29, float b30, float wh30, float& h30,
                     float*& optr, bool st, int pidx) {
#pragma unroll
  for (int tt = 0; tt < CH; tt++) {
    const int IN2 = SL * 48 + tt * 12;
    const int PV2 = tt ? (SL * 48 + (tt - 1) * 12) : ((1 - SL) * 48 + 36);
    f2 a; a.x = b29; a.y = 0.f;
    acc12h(a, y8r + IN2, wi29);
    acc12h(a, y9r + PV2, wh29);
    const float h = ftanh(redsum(a, pidx));
    y9w[IN2] = h;
    f2 a3; a3.x = b30; a3.y = 0.f;
    acc12h(a3, y9r + IN2, wi30);
    const float s3 = redsum(a3, pidx);
    h30 = ftanh(fmaf(h30, wh30, s3));
    if (st) optr[tt * B_] = h30;
  }
  optr += CH * B_;
}

template <bool PH>
DEVI void tail29(const P& p, int w, int b, int lane, float* y2f) {
  const int jj = lane & 31;
  const bool act = jj < 10;
  const bool hi = lane >= 32;
  const int pidx = (lane ^ 32) << 2;
  const int j = act ? jj : 9;
  const int ko2 = hi ? 6 : 0;
  const bool st = (lane == 0);
  f2 wi29[3], wh29[3], wi30[3];
#pragma unroll
  for (int k = 0; k < 3; k++) {
    const int i0 = ko2 + 2 * k, i1 = i0 + 1;
    wi29[k].x = i0 < 10 ? p.wih[29][j * 10 + i0] : 0.f; wi29[k].y = i1 < 10 ? p.wih[29][j * 10 + i1] : 0.f;
    wh29[k].x = i0 < 10 ? p.whh[29][j * 10 + i0] : 0.f; wh29[k].y = i1 < 10 ? p.whh[29][j * 10 + i1] : 0.f;
    wi30[k].x = i0 < 10 ? p.wih[30][i0] : 0.f;          wi30[k].y = i1 < 10 ? p.wih[30][i1] : 0.f;
  }
  const float b29 = hi ? 0.f : (p.bih[29][j] + p.bhh[29][j]);
  const float b30 = hi ? 0.f : (p.bih[30][0] + p.bhh[30][0]);
  const float wh30 = p.whh[30][0];   // used post-reduction: full value in ALL lanes
  float h30 = 0.0f;
  const float* y8r = y2f + 8 * Y2L + ko2;
  const float* y9r = y2f + 9 * Y2L + ko2;
  float*       y9w = y2f + 9 * Y2L + j;
  float* optr = p.out + b;

  for (int s = 0; s < NSTEP2; s += 2) {
    if ((unsigned)(s - w) < (unsigned)NCH && act)
      tail_chunk<PH ? 1 : 0>(y8r, y9r, y9w, wi29, wh29, wi30, b29, b30, wh30, h30, optr, st, pidx);
    __syncthreads();
    if ((unsigned)(s + 1 - w) < (unsigned)NCH && act)
      tail_chunk<PH ? 0 : 1>(y8r, y9r, y9w, wi29, wh29, wi30, b29, b30, wh30, h30, optr, st, pidx);
    __syncthreads();
  }
  if (st) p.out[T_ * B_ + b] = h30;  // hT
}

// ================= kernel =================
__global__ __launch_bounds__(960, 4) void rnn_fused(P p) {
  __shared__ alignas(16) float xbuf[2 * CH * XROW];  // 2.2 KB staged x
  __shared__ alignas(16) float xw[2 * CH * 20];      // 0.6 KB projected input
  __shared__ alignas(16) float y1[20 * Y1L];         // 12.8 KB stack1 rings
  __shared__ alignas(16) float y2[10 * Y2L];         //  3.8 KB stack2 rings
  const int w = threadIdx.x >> 6, lane = threadIdx.x & 63, b = blockIdx.x;
  if (w == 0)       stage_proj(p, b, lane, xbuf, xw);
  else if (w == 1)  pair_s1<true, true>(0, 1, p, lane, y1, xw);
  else if (w <= 10) {
    const int la = 2 * (w - 1);
    if (w & 1) pair_s1<true, false>(la, w, p, lane, y1, xw);
    else       pair_s1<false, false>(la, w, p, lane, y1, xw);
  }
  else if (w == 11) tri20<true>(p, 11, lane, y1, y2);
  else if (w == 12) tri_s2<false>(23, 12, p, lane, y2);
  else if (w == 13) tri_s2<true>(26, 13, p, lane, y2);
  else              tail29<false>(p, 14, b, lane, y2);
}

extern "C" void kernel_launch(void* const* d_in, const int* in_sizes, int n_in,
                              void* d_out, int out_size, void* d_ws, size_t ws_size,
                              hipStream_t stream) {
  (void)in_sizes; (void)out_size; (void)d_ws; (void)ws_size;
  if (n_in < 21) return;
  P p{};
  p.x  = (const float*)d_in[0];
  p.w1 = (const float*)d_in[1];    // s1_wih0 (20x64)
  p.b1 = (const float*)d_in[3];    // s1_bih0
  p.wih[0] = nullptr;              p.whh[0] = (const float*)d_in[2];
  p.bih[0] = nullptr;              p.bhh[0] = (const float*)d_in[4];
  for (int l = 1; l < 20; l++) {
    p.wih[l] = (const float*)d_in[5] + (l - 1) * 400;
    p.whh[l] = (const float*)d_in[6] + (l - 1) * 400;
    p.bih[l] = (const float*)d_in[7] + (l - 1) * 20;
    p.bhh[l] = (const float*)d_in[8] + (l - 1) * 20;
  }
  p.wih[20] = (const float*)d_in[9];   p.whh[20] = (const float*)d_in[10];
  p.bih[20] = (const float*)d_in[11];  p.bhh[20] = (const float*)d_in[12];
  for (int l = 21; l < 30; l++) {
    p.wih[l] = (const float*)d_in[13] + (l - 21) * 100;
    p.whh[l] = (const float*)d_in[14] + (l - 21) * 100;
    p.bih[l] = (const float*)d_in[15] + (l - 21) * 10;
    p.bhh[l] = (const float*)d_in[16] + (l - 21) * 10;
  }
  p.wih[30] = (const float*)d_in[17];  p.whh[30] = (const float*)d_in[18];
  p.bih[30] = (const float*)d_in[19];  p.bhh[30] = (const float*)d_in[20];
  p.out = (float*)d_out;

  rnn_fused<<<B_, 960, 0, stream>>>(p);
}